// Round 16
// baseline (1424.235 us; speedup 1.0000x reference)
//
#include <hip/hip_runtime.h>
#include <hip/hip_bf16.h>

typedef unsigned short bf16_t;
typedef __bf16 bf16x8 __attribute__((ext_vector_type(8)));
typedef float f32x4 __attribute__((ext_vector_type(4)));
typedef unsigned short ushort8_t __attribute__((ext_vector_type(8)));

__device__ __forceinline__ unsigned short f2bf(float x){
  union { __hip_bfloat16 h; unsigned short u; } c;
  c.h = __float2bfloat16(x);
  return c.u;
}
__device__ __forceinline__ float bf2f(bf16_t u){
  union { unsigned short u; __hip_bfloat16 h; } c;
  c.u = u;
  return __bfloat162float(c.h);
}

// ---------------------------------------------------------------------------
// HYBRID bf16 MFMA GEMM: 128x128 tile, BK=64, 4 waves (2x2), 64x64 per wave.
//  - A: row-major bf16, staged via LDS (R13's verified path): 4 ds_write +
//    8 ds_read b128 per thread-step, XOR-swizzled (slot s holds k-group
//    s^(row&7)), conflict-free.
//  - B: fragment-packed (R15's verified layout), loaded DIRECT from global/L2
//    to MFMA registers - no LDS, no ds ops. Halves the LDS-pipe issue that
//    bounded R13 (~2300 cyc/block-step -> ~1150).
// Frag layout: 1KB slab = 16 rows x 32 k; lane l holds row l&15, k-group l>>4.
// One raw s_barrier + lgkmcnt(0) per step (A only); B ordering via reg deps.
// 32 KB LDS, ~200 VGPR, __launch_bounds__(256,2) -> 2 blocks/CU (8 waves).
// MAP=0: blockIdx=(col,row,ks) -> id%8=col%8.  MAP=1: (ks,col,row), id%8=ks.
// ACT: 0 = f32 partial store at ks*csplit; 4 = bf16 store with bias.
// Kchunk: elements, multiple of 64.
// ---------------------------------------------------------------------------
template<int ACT, int MAP>
__global__ __launch_bounds__(256, 2)
void gemm_hyb(const bf16_t* __restrict__ A, int lda,
              const bf16_t* __restrict__ Bpk, int KTB,
              float* __restrict__ C, int ldc, size_t csplit,
              const float* __restrict__ bias,
              int M, int Kchunk)
{
  __shared__ __align__(16) bf16_t As[2][128*64];   // 2 x 16 KB
  const int tid = threadIdx.x;
  const int w = tid >> 6, lane = tid & 63;
  const int wm = w >> 1, wn = w & 1;
  const int lr = lane & 15, kq = lane >> 4;
  int bcol, brow, bks;
  if (MAP == 0) { bcol = blockIdx.x; brow = blockIdx.y; bks = blockIdx.z; }
  else          { bks = blockIdx.x;  bcol = blockIdx.y; brow = blockIdx.z; }
  const int gm0 = brow * 128, gn0 = bcol * 128;
  const int k0 = bks * Kchunk;
  const int nt = Kchunk >> 6;                 // K=64 steps
  const int ksB = bks * (Kchunk >> 5);        // B starting 32-slab

  // A staging (R13): unit u = tid + 256j (j=0..3); row u>>3, slot u&7,
  // source k-group (u&7)^(row&7); LDS elem addr u*8 (lane-linear, no conflict)
  const bf16_t *pA0, *pA1, *pA2, *pA3;
  {
    const int u0 = tid,       r0 = u0 >> 3, g0 = (u0 & 7) ^ (r0 & 7);
    const int u1 = tid + 256, r1 = u1 >> 3, g1 = (u1 & 7) ^ (r1 & 7);
    const int u2 = tid + 512, r2 = u2 >> 3, g2 = (u2 & 7) ^ (r2 & 7);
    const int u3 = tid + 768, r3 = u3 >> 3, g3 = (u3 & 7) ^ (r3 & 7);
    pA0 = A + (size_t)min(gm0 + r0, M-1)*lda + k0 + g0*8;
    pA1 = A + (size_t)min(gm0 + r1, M-1)*lda + k0 + g1*8;
    pA2 = A + (size_t)min(gm0 + r2, M-1)*lda + k0 + g2*8;
    pA3 = A + (size_t)min(gm0 + r3, M-1)*lda + k0 + g3*8;
  }
  bf16_t* Al = &As[0][0] + tid*8;
  ushort8_t va0, va1, va2, va3;

  // B fragment pointers: n-group = bcol*8 + wn*4 + q
  const bf16_t* pb[4];
#pragma unroll
  for (int q = 0; q < 4; q++)
    pb[q] = Bpk + ((size_t)(bcol*8 + wn*4 + q)*KTB + ksB)*512 + lane*8;

  bf16x8 b[2][8];                             // [buf][ks*4+q]
  f32x4 acc[4][4] = {};

#define LDA(t) do { \
    va0 = *(const ushort8_t*)(pA0 + (size_t)(t)*64); \
    va1 = *(const ushort8_t*)(pA1 + (size_t)(t)*64); \
    va2 = *(const ushort8_t*)(pA2 + (size_t)(t)*64); \
    va3 = *(const ushort8_t*)(pA3 + (size_t)(t)*64); \
  } while(0)
#define WRA(bf) do { \
    *(ushort8_t*)(Al + (bf)*8192)        = va0; \
    *(ushort8_t*)(Al + (bf)*8192 + 2048) = va1; \
    *(ushort8_t*)(Al + (bf)*8192 + 4096) = va2; \
    *(ushort8_t*)(Al + (bf)*8192 + 6144) = va3; } while(0)
#define LDB(BUF, t) do { \
    _Pragma("unroll") \
    for (int q = 0; q < 4; q++) { \
      b[BUF][q]     = *(const bf16x8*)(pb[q] + (size_t)(t)*1024); \
      b[BUF][q + 4] = *(const bf16x8*)(pb[q] + (size_t)(t)*1024 + 512); \
    } } while(0)

  LDA(0); WRA(0);
  LDB(0, 0);
  if (nt > 1) { LDB(1, 1); LDA(1); }
  asm volatile("s_waitcnt lgkmcnt(0)" ::: "memory");
  __builtin_amdgcn_s_barrier();
  __builtin_amdgcn_sched_barrier(0);

  const int ph = lr & 7;                      // XOR term for phys A slot
  for (int t = 0; t < nt; ++t) {
    const int cb = t & 1;
    const bf16_t* Ab = &As[0][0] + cb*8192;
    bf16x8 af[2][4];
#pragma unroll
    for (int ks = 0; ks < 2; ks++) {
      const int phys = (ks*4 + kq) ^ ph;
#pragma unroll
      for (int mi = 0; mi < 4; mi++)
        af[ks][mi] = *(const bf16x8*)(Ab + (wm*64 + mi*16 + lr)*64 + phys*8);
    }
    if (t + 1 < nt) WRA(cb ^ 1);     // A tile t+1 (regs landed; auto vmcnt)
    if (t + 2 < nt) LDA(t + 2);      // issue A loads for t+2
    __builtin_amdgcn_s_setprio(1);
#pragma unroll
    for (int ks = 0; ks < 2; ks++)
#pragma unroll
      for (int mi = 0; mi < 4; mi++)
#pragma unroll
        for (int ni = 0; ni < 4; ni++)
          acc[mi][ni] = __builtin_amdgcn_mfma_f32_16x16x32_bf16(
              af[ks][mi], b[cb][ks*4 + ni], acc[mi][ni], 0, 0, 0);
    __builtin_amdgcn_s_setprio(0);
    if (t + 2 < nt) LDB(cb, t + 2);  // refill the just-consumed B buffer
    asm volatile("s_waitcnt lgkmcnt(0)" ::: "memory");
    __builtin_amdgcn_s_barrier();
    __builtin_amdgcn_sched_barrier(0);
  }
#undef LDA
#undef WRA
#undef LDB

  // epilogue: D row = kq*4 + i, col = lane&15 per 16x16 frag
#pragma unroll
  for (int mi = 0; mi < 4; mi++) {
#pragma unroll
    for (int ni = 0; ni < 4; ni++) {
      const int col = gn0 + wn*64 + ni*16 + lr;
      const float bv = (ACT == 4) ? bias[col] : 0.f;
#pragma unroll
      for (int i = 0; i < 4; i++) {
        const int row = gm0 + wm*64 + mi*16 + kq*4 + i;
        if (row < M) {
          const float v = acc[mi][ni][i] + bv;
          if (ACT == 4) ((bf16_t*)C)[(size_t)row*ldc + col] = f2bf(v);
          else C[(size_t)bks*csplit + (size_t)row*ldc + col] = v;
        }
      }
    }
  }
}

// pack B (f32 [K][srcldN], transposed) -> fragment tiles for n16 groups.
__global__ void pack_bfrag(const float* __restrict__ src, bf16_t* __restrict__ dst,
                           int srcldN, int KT, int n0t, size_t in_batch, int ogb)
{
  const int ntb = blockIdx.x, kt = blockIdx.y, bz = blockIdx.z;
  src += (size_t)bz * in_batch;
  const int ng0 = n0t + bz*ogb + ntb*8;
  __shared__ float s[32][132];
  for (int i = threadIdx.x; i < 4096; i += 256) {
    const int kl = i >> 7, nl = i & 127;
    s[kl][nl] = src[(size_t)(kt*32 + kl)*srcldN + ntb*128 + nl];
  }
  __syncthreads();
  for (int u = threadIdx.x; u < 512; u += 256) {
    const int t = u >> 6, ln = u & 63;
    const int n = t*16 + (ln & 15), kq = ln >> 4;
    ushort4 v0, v1;
    v0 = make_ushort4(f2bf(s[kq*8+0][n]), f2bf(s[kq*8+1][n]), f2bf(s[kq*8+2][n]), f2bf(s[kq*8+3][n]));
    v1 = make_ushort4(f2bf(s[kq*8+4][n]), f2bf(s[kq*8+5][n]), f2bf(s[kq*8+6][n]), f2bf(s[kq*8+7][n]));
    bf16_t* dt = dst + ((size_t)(ng0 + t)*KT + kt)*512 + ln*8;
    *(ushort4*)dt = v0;
    *(ushort4*)(dt + 4) = v1;
  }
}

// sum split-K partials, add bias, write prop f32 + X right half bf16
__global__ void reduce_compress(const float* __restrict__ part, const float* __restrict__ bias,
                                float* __restrict__ prop, bf16_t* __restrict__ xr)
{
  const int idx = blockIdx.x*256 + threadIdx.x;   // < 921600
  const int m = idx >> 10, d = idx & 1023;
  float v = bias[d];
#pragma unroll
  for (int z = 0; z < 8; z++) v += part[(size_t)z*921600 + idx];
  prop[idx] = v;
  xr[(size_t)m*2048 + 1024 + d] = f2bf(v);
}

// RZ split-2 reduce: v = sigmoid(p0+p1+bias). col<1024: Xh_right = bf16(v*prop)
// col>=1024: Zbuf = v.
__global__ void reduce_rz(const float* __restrict__ part, const float* __restrict__ bias,
                          const float* __restrict__ prop, float* __restrict__ Zbuf,
                          bf16_t* __restrict__ Xh)
{
  const int idx = blockIdx.x*256 + threadIdx.x;   // < 1843200
  const int m = idx >> 11, c = idx & 2047;
  float v = part[idx] + part[1843200 + idx] + bias[c];
  v = 1.f / (1.f + __expf(-v));
  if (c < 1024) Xh[(size_t)m*2048 + 1024 + c] = f2bf(v * prop[(size_t)m*1024 + c]);
  else          Zbuf[(size_t)m*1024 + (c - 1024)] = v;
}

// h split-4 reduce: h_hat = tanh(sum+bh); prop = (1-z)*prop + z*h_hat
__global__ void reduce_h(const float* __restrict__ part, const float* __restrict__ bias,
                         const float* __restrict__ Zbuf, float* __restrict__ prop,
                         bf16_t* __restrict__ X)
{
  const int idx = blockIdx.x*256 + threadIdx.x;   // < 921600
  const int m = idx >> 10, d = idx & 1023;
  float v = bias[d];
#pragma unroll
  for (int z = 0; z < 4; z++) v += part[(size_t)z*921600 + idx];
  v = tanhf(v);
  const float zz = Zbuf[idx];
  const float pn = (1.f - zz)*prop[idx] + zz*v;
  prop[idx] = pn;
  X[(size_t)m*2048 + 1024 + d] = f2bf(pn);
}

// u_row[e][h] = sum_d W_edge[e][h][d]*W_att[e][d]; u_col with W_att[e][1024+d]
__global__ void compute_u(const float* __restrict__ We, const float* __restrict__ Wa,
                          float* __restrict__ u_row, float* __restrict__ u_col)
{
  const int w = threadIdx.x >> 6, lane = threadIdx.x & 63;
  const int idx = blockIdx.x*4 + w;               // grid=1792 -> idx<7168
  const int e = idx >> 10, h = idx & 1023;
  const float* wep = We + ((size_t)e*1024 + h)*1024;
  const float* wr  = Wa + (size_t)e*2048;
  const float* wc  = wr + 1024;
  float ar = 0.f, ac = 0.f;
#pragma unroll
  for (int t = 0; t < 16; t++) {
    const float v = wep[lane + 64*t];
    ar += v*wr[lane + 64*t];
    ac += v*wc[lane + 64*t];
  }
  for (int off = 32; off; off >>= 1) { ar += __shfl_down(ar, off); ac += __shfl_down(ac, off); }
  if (lane == 0) { u_row[idx] = ar; u_col[idx] = ac; }
}

// crc[e] = b_edge[e].Wa_row[e], crc[7+e] = b_edge[e].Wa_col[e]
__global__ void crc_kernel(const float* __restrict__ be, const float* __restrict__ Wa,
                           float* __restrict__ crc)
{
  const int w = threadIdx.x >> 6, lane = threadIdx.x & 63;
  for (int idx = w; idx < 14; idx += 4) {
    const int e = idx >> 1, which = idx & 1;
    const float* bp = be + e*1024;
    const float* wp = Wa + (size_t)e*2048 + which*1024;
    float a = 0.f;
#pragma unroll
    for (int t = 0; t < 16; t++) a += bp[lane + 64*t]*wp[lane + 64*t];
    for (int off = 32; off; off >>= 1) a += __shfl_down(a, off);
    if (lane == 0) crc[which*7 + e] = a;
  }
}

// per (b,e): scores
__global__ void attn_kernel(const float* __restrict__ prop, const float* __restrict__ u_row,
                            const float* __restrict__ u_col, const float* __restrict__ crc,
                            const float* __restrict__ b_att, float* __restrict__ scores)
{
  const int b = blockIdx.x, e = blockIdx.y;
  __shared__ float rowv[15], colv[15];
  const int w = threadIdx.x >> 6, lane = threadIdx.x & 63;
  const float* ur = u_row + (size_t)e*1024;
  const float* uc = u_col + (size_t)e*1024;
  for (int n = w; n < 15; n += 4) {
    const float* pr = prop + (size_t)(b*15 + n)*1024;
    float ar = 0.f, ac = 0.f;
#pragma unroll
    for (int t = 0; t < 16; t++) {
      const float pv = pr[lane + 64*t];
      ar += pv*ur[lane + 64*t];
      ac += pv*uc[lane + 64*t];
    }
    for (int off = 32; off; off >>= 1) { ar += __shfl_down(ar, off); ac += __shfl_down(ac, off); }
    if (lane == 0) { rowv[n] = ar; colv[n] = ac; }
  }
  __syncthreads();
  const float base = b_att[e] + crc[e] + crc[7 + e];
  for (int idx = threadIdx.x; idx < 225; idx += 256) {
    const int i = idx/15, j = idx - i*15;
    const float s = 1.f / (1.f + __expf(-(rowv[i] + colv[j] + base)));
    scores[((size_t)(b*7 + e)*15 + i)*15 + j] = s;
  }
}

// merged[b,i,d] = sum_e sum_j scores[b,e,i,j]*msg[b*15+j, e*1024+d]
// -> X left half AND Xh left half (bf16, row-major)
__global__ void merged_kernel(const bf16_t* __restrict__ msg, const float* __restrict__ scores,
                              bf16_t* __restrict__ X, bf16_t* __restrict__ Xh)
{
  const int b = blockIdx.x, c = blockIdx.y;   // c: 128-wide d-chunk, 8 chunks
  __shared__ float ms[15*7*128];              // [j][e][dl]
  __shared__ float sc[1575];                  // [e][i][j]
  for (int q = threadIdx.x; q < 3360; q += 256) {
    const int idx = q*4;
    const int j = idx / 896;
    const int rem = idx - j*896;
    const int e = rem >> 7, dl = rem & 127;
    const ushort4 v = *(const ushort4*)(msg + (size_t)(b*15 + j)*7168 + e*1024 + c*128 + dl);
    ms[idx]   = bf2f(v.x);
    ms[idx+1] = bf2f(v.y);
    ms[idx+2] = bf2f(v.z);
    ms[idx+3] = bf2f(v.w);
  }
  for (int idx = threadIdx.x; idx < 1575; idx += 256)
    sc[idx] = scores[(size_t)b*1575 + idx];
  __syncthreads();
  for (int oi = threadIdx.x; oi < 1920; oi += 256) {
    const int i = oi >> 7, dl = oi & 127;
    float acc = 0.f;
#pragma unroll
    for (int e = 0; e < 7; e++)
#pragma unroll
      for (int j = 0; j < 15; j++)
        acc += sc[(e*15 + i)*15 + j] * ms[j*896 + e*128 + dl];
    const bf16_t o = f2bf(acc);
    X [(size_t)(b*15 + i)*2048 + c*128 + dl] = o;
    Xh[(size_t)(b*15 + i)*2048 + c*128 + dl] = o;
  }
}

__global__ void cast_f32_bf16(const float4* __restrict__ in, ushort4* __restrict__ out, int n4)
{
  int i = blockIdx.x*256 + threadIdx.x;
  const int stride = gridDim.x*256;
  for (; i < n4; i += stride) {
    const float4 v = in[i];
    out[i] = make_ushort4(f2bf(v.x), f2bf(v.y), f2bf(v.z), f2bf(v.w));
  }
}

__global__ void cat2_kernel(const float* __restrict__ a, const float* __restrict__ b,
                            float* __restrict__ o)
{
  const int i = blockIdx.x*256 + threadIdx.x;
  if (i < 1024) o[i] = a[i];
  else if (i < 2048) o[i] = b[i - 1024];
}

// final outputs from last-iteration scores
__global__ void finalize_kernel(const float* __restrict__ scores, float* __restrict__ out)
{
  const int b = blockIdx.x;   // 0..59
  __shared__ float sc[1575];
  __shared__ float act[105];
  __shared__ float asum[15];
  __shared__ float t2[7];
  for (int idx = threadIdx.x; idx < 1575; idx += 256)
    sc[idx] = scores[(size_t)b*1575 + idx];
  __syncthreads();
  for (int idx = threadIdx.x; idx < 105; idx += 256) {
    const int i = idx/7, e = idx - i*7;
    float a = 0.f;
#pragma unroll
    for (int j = 0; j < 15; j++)
      a += (1.f - sc[i*15 + j]) * sc[(e*15 + i)*15 + j];
    act[idx] = a;
    out[(size_t)b*105 + idx] = a;
  }
  for (int idx = threadIdx.x; idx < 225; idx += 256) {
    const int i = idx/15, j = idx - i*15;
    out[6660 + (size_t)b*225 + idx] = 1.f - sc[i*15 + j];
  }
  if (threadIdx.x < 15) {
    const int i = threadIdx.x;
    float s = 0.f;
#pragma unroll
    for (int j = 0; j < 15; j++) s += 1.f - sc[i*15 + j];
    asum[i] = s;
  }
  __syncthreads();
  if (threadIdx.x < 7) {
    const int e = threadIdx.x;
    float t = 0.f;
#pragma unroll
    for (int i = 0; i < 15; i++) t += act[i*7 + e]*asum[i];
    t2[e] = t;
  }
  __syncthreads();
  if (threadIdx.x == 0) {
    float mx = -1e30f;
    for (int e = 1; e < 7; e++) mx = fmaxf(mx, t2[e]);
    float s = 0.f, ex[6];
    for (int e = 1; e < 7; e++) { ex[e-1] = __expf(t2[e] - mx); s += ex[e-1]; }
    for (int e = 1; e < 7; e++) out[6300 + (size_t)b*6 + (e-1)] = ex[e-1]/s;
  }
}

extern "C" void kernel_launch(void* const* d_in, const int* in_sizes, int n_in,
                              void* d_out, int out_size, void* d_ws, size_t ws_size,
                              hipStream_t stream)
{
  const float* pose = (const float*)d_in[0];
  const float* Wc   = (const float*)d_in[1];
  const float* bc   = (const float*)d_in[2];
  const float* We   = (const float*)d_in[3];
  const float* be   = (const float*)d_in[4];
  const float* Wa   = (const float*)d_in[5];
  const float* ba   = (const float*)d_in[6];
  const float* Wr   = (const float*)d_in[7];
  const float* br   = (const float*)d_in[8];
  const float* Wz   = (const float*)d_in[9];
  const float* bz   = (const float*)d_in[10];
  const float* Wh   = (const float*)d_in[11];
  const float* bh   = (const float*)d_in[12];
  float* out = (float*)d_out;

  // ---- workspace carving ----
  char* p = (char*)d_ws;
  auto alloc = [&](size_t b) { char* r = p; p += (b + 255) & ~(size_t)255; return r; };
  bf16_t* Wedgep = (bf16_t*)alloc(448ull*32*1024);   // 14.7 MB frag [448 ng][32 kt]
  bf16_t* Wrzp   = (bf16_t*)alloc(128ull*64*1024);   //  8.4 MB frag [128 ng][64 kt]
  bf16_t* Whp    = (bf16_t*)alloc(64ull*64*1024);    //  4.2 MB frag
  bf16_t* X      = (bf16_t*)alloc(900ull*2048*2);    //  3.7 MB [merged|prop] row-major
  float*  prop   = (float*) alloc(900ull*1024*4);    //  3.7 MB f32 state
  float*  scores = (float*) alloc(60ull*7*15*15*4);
  float*  u_row  = (float*) alloc(7168*4);
  float*  u_col  = (float*) alloc(7168*4);
  float*  crc    = (float*) alloc(64);
  float*  brzv   = (float*) alloc(2048*4);
  // phase-union region (128 MB):
  // phase1 (compress): Abf 46.08 @0 | Wcp 52.4 @46.08M | partial 29.5 @98.5M
  // phase2 (iters): msgb 12.9 @0 | Zbuf @12.9M | Xh @16.6M | partRZ @20.3M
  //                 | partH @49.8M
  char* r1 = alloc(128000000ull);
  bf16_t* Abf     = (bf16_t*)r1;                     // 900x25600 bf16 row-major
  bf16_t* Wcp     = (bf16_t*)(r1 + 46080000ull);     // frag [64 ng][800 kt]
  float*  partial = (float*) (r1 + 46080000ull + 52428800ull);
  bf16_t* msgb    = (bf16_t*)r1;
  float*  Zbuf    = (float*) (r1 + 12902400ull);
  bf16_t* Xh      = (bf16_t*)(r1 + 16588800ull);
  float*  partRZ  = (float*) (r1 + 20275200ull);     // 2 x 900 x 2048 f32
  float*  partH   = (float*) (r1 + 49766400ull);     // 4 x 900 x 1024 f32

  // ---- precompute ----
  compute_u<<<1792, 256, 0, stream>>>(We, Wa, u_row, u_col);
  crc_kernel<<<1, 256, 0, stream>>>(be, Wa, crc);
  cat2_kernel<<<8, 256, 0, stream>>>(br, bz, brzv);
  cast_f32_bf16<<<2048, 256, 0, stream>>>((const float4*)pose, (ushort4*)Abf, 23040000/4);
  pack_bfrag<<<dim3(8,800), 256, 0, stream>>>(Wc, Wcp, 1024, 800, 0, 0, 0);
  pack_bfrag<<<dim3(8,32,7), 256, 0, stream>>>(We, Wedgep, 1024, 32, 0,
                                               1024ull*1024, 64);
  pack_bfrag<<<dim3(8,64), 256, 0, stream>>>(Wr, Wrzp, 1024, 64, 0, 0, 0);
  pack_bfrag<<<dim3(8,64), 256, 0, stream>>>(Wz, Wrzp, 1024, 64, 64, 0, 0);
  pack_bfrag<<<dim3(8,64), 256, 0, stream>>>(Wh, Whp, 1024, 64, 0, 0, 0);

  // compress: prop = pose @ W_compress + b_compress  (MAP1, ks=8, nt=50)
  gemm_hyb<0,1><<<dim3(8,8,8), 256, 0, stream>>>(Abf, 25600, Wcp, 800,
      partial, 1024, 921600ull, nullptr, 900, 3200);
  reduce_compress<<<3600, 256, 0, stream>>>(partial, bc, prop, X);

  // ---- 6 recurrent iterations (last one: scores only) ----
  for (int it = 0; it < 6; it++) {
    attn_kernel<<<dim3(60,7), 256, 0, stream>>>(prop, u_row, u_col, crc, ba, scores);
    if (it == 5) break;
    // msg = prop @ W_edge + b_edge  (A = X right half, row-major; MAP0, nt=16)
    gemm_hyb<4,0><<<dim3(56,8,1), 256, 0, stream>>>(X + 1024, 2048, Wedgep, 32,
        (float*)msgb, 7168, 0, be, 900, 1024);
    merged_kernel<<<dim3(60,8), 256, 0, stream>>>(msgb, scores, X, Xh);
    // [r|z] = X @ [Wr|Wz]  (MAP0, ks=2, nt=16)
    gemm_hyb<0,0><<<dim3(16,8,2), 256, 0, stream>>>(X, 2048, Wrzp, 64,
        partRZ, 2048, 1843200ull, nullptr, 900, 1024);
    reduce_rz<<<7200, 256, 0, stream>>>(partRZ, brzv, prop, Zbuf, Xh);
    // h = Xh @ Wh  (MAP0, ks=4, nt=8)
    gemm_hyb<0,0><<<dim3(8,8,4), 256, 0, stream>>>(Xh, 2048, Whp, 64,
        partH, 1024, 921600ull, nullptr, 900, 512);
    reduce_h<<<3600, 256, 0, stream>>>(partH, bh, Zbuf, prop, X);
  }

  finalize_kernel<<<60, 256, 0, stream>>>(scores, out);
}

// Round 17
// 660.273 us; speedup vs baseline: 2.1570x; 2.1570x over previous
//
#include <hip/hip_runtime.h>
#include <hip/hip_bf16.h>

typedef unsigned short bf16_t;
typedef __bf16 bf16x8 __attribute__((ext_vector_type(8)));
typedef float f32x4 __attribute__((ext_vector_type(4)));
typedef unsigned short ushort8_t __attribute__((ext_vector_type(8)));

__device__ __forceinline__ unsigned short f2bf(float x){
  union { __hip_bfloat16 h; unsigned short u; } c;
  c.h = __float2bfloat16(x);
  return c.u;
}
__device__ __forceinline__ float bf2f(bf16_t u){
  union { unsigned short u; __hip_bfloat16 h; } c;
  c.u = u;
  return __bfloat162float(c.h);
}

// ---------------------------------------------------------------------------
// HYBRID bf16 MFMA GEMM: 128x128 tile, BK=64, 4 waves (2x2), 64x64 per wave.
//  - A: row-major bf16 via LDS (R13 path): 4 ds_write + 8 ds_read b128 per
//    thread-step, XOR-swizzle slot s = kgroup^(row&7), conflict-free.
//  - B: fragment-packed, DIRECT global->reg (no LDS). Halves LDS-pipe issue.
// ALL double-buffer indices are COMPILE-TIME (R16 bug: runtime-indexed
// b[cb][..] was demoted to scratch -> 823 MB spill traffic; rule #20).
// K-loop unrolled x2 with literal buffer constants; nt must be EVEN.
// Frag layout: 1KB slab = 16 rows x 32 k; lane l holds row l&15, kgroup l>>4.
// 32 KB LDS, __launch_bounds__(256,2).
// MAP=0: blockIdx=(col,row,ks) -> id%8=col%8.  MAP=1: (ks,col,row), id%8=ks.
// ACT: 0 = f32 partial store at ks*csplit; 4 = bf16 store with bias.
// Kchunk: elements, multiple of 128 (nt even).
// ---------------------------------------------------------------------------
template<int ACT, int MAP>
__global__ __launch_bounds__(256, 2)
void gemm_hyb(const bf16_t* __restrict__ A, int lda,
              const bf16_t* __restrict__ Bpk, int KTB,
              float* __restrict__ C, int ldc, size_t csplit,
              const float* __restrict__ bias,
              int M, int Kchunk)
{
  __shared__ __align__(16) bf16_t As[2][128*64];   // 2 x 16 KB
  const int tid = threadIdx.x;
  const int w = tid >> 6, lane = tid & 63;
  const int wm = w >> 1, wn = w & 1;
  const int lr = lane & 15, kq = lane >> 4;
  int bcol, brow, bks;
  if (MAP == 0) { bcol = blockIdx.x; brow = blockIdx.y; bks = blockIdx.z; }
  else          { bks = blockIdx.x;  bcol = blockIdx.y; brow = blockIdx.z; }
  const int gm0 = brow * 128, gn0 = bcol * 128;
  const int k0 = bks * Kchunk;
  const int nt = Kchunk >> 6;                 // K=64 steps (EVEN)
  const int ksB = bks * (Kchunk >> 5);        // B starting 32-slab

  // A staging: unit u = tid + 256j; row u>>3, slot u&7, src kgroup (u&7)^(row&7)
  const bf16_t *pA0, *pA1, *pA2, *pA3;
  {
    const int u0 = tid,       r0 = u0 >> 3, g0 = (u0 & 7) ^ (r0 & 7);
    const int u1 = tid + 256, r1 = u1 >> 3, g1 = (u1 & 7) ^ (r1 & 7);
    const int u2 = tid + 512, r2 = u2 >> 3, g2 = (u2 & 7) ^ (r2 & 7);
    const int u3 = tid + 768, r3 = u3 >> 3, g3 = (u3 & 7) ^ (r3 & 7);
    pA0 = A + (size_t)min(gm0 + r0, M-1)*lda + k0 + g0*8;
    pA1 = A + (size_t)min(gm0 + r1, M-1)*lda + k0 + g1*8;
    pA2 = A + (size_t)min(gm0 + r2, M-1)*lda + k0 + g2*8;
    pA3 = A + (size_t)min(gm0 + r3, M-1)*lda + k0 + g3*8;
  }
  bf16_t* Al = &As[0][0] + tid*8;
  ushort8_t va0, va1, va2, va3;

  const bf16_t* pb[4];
#pragma unroll
  for (int q = 0; q < 4; q++)
    pb[q] = Bpk + ((size_t)(bcol*8 + wn*4 + q)*KTB + ksB)*512 + lane*8;

  bf16x8 b0[8], b1[8];                        // two static B buffers
  f32x4 acc[4][4] = {};

#define LDA(t) do { \
    va0 = *(const ushort8_t*)(pA0 + (size_t)(t)*64); \
    va1 = *(const ushort8_t*)(pA1 + (size_t)(t)*64); \
    va2 = *(const ushort8_t*)(pA2 + (size_t)(t)*64); \
    va3 = *(const ushort8_t*)(pA3 + (size_t)(t)*64); \
  } while(0)
#define WRA(bf) do { \
    *(ushort8_t*)(Al + (bf)*8192)        = va0; \
    *(ushort8_t*)(Al + (bf)*8192 + 2048) = va1; \
    *(ushort8_t*)(Al + (bf)*8192 + 4096) = va2; \
    *(ushort8_t*)(Al + (bf)*8192 + 6144) = va3; } while(0)
#define LDB(ARR, t) do { \
    _Pragma("unroll") \
    for (int q = 0; q < 4; q++) { \
      ARR[q]     = *(const bf16x8*)(pb[q] + (size_t)(t)*1024); \
      ARR[q + 4] = *(const bf16x8*)(pb[q] + (size_t)(t)*1024 + 512); \
    } } while(0)
// one K=64 step using LDS buffer SB and B array ARR; prefetches A into
// buffer SB^1 (tile t+1) and issues LDA/LDB for tile t+2 into ARR.
#define STEP(SB, ARR, t) do { \
    const bf16_t* Ab = &As[SB][0]; \
    bf16x8 af[2][4]; \
    _Pragma("unroll") \
    for (int ks = 0; ks < 2; ks++) { \
      const int phys = (ks*4 + kq) ^ ph; \
      _Pragma("unroll") \
      for (int mi = 0; mi < 4; mi++) \
        af[ks][mi] = *(const bf16x8*)(Ab + (wm*64 + mi*16 + lr)*64 + phys*8); \
    } \
    if ((t) + 1 < nt) WRA(SB ^ 1); \
    if ((t) + 2 < nt) LDA((t) + 2); \
    __builtin_amdgcn_s_setprio(1); \
    _Pragma("unroll") \
    for (int ks = 0; ks < 2; ks++) \
      _Pragma("unroll") \
      for (int mi = 0; mi < 4; mi++) \
        _Pragma("unroll") \
        for (int ni = 0; ni < 4; ni++) \
          acc[mi][ni] = __builtin_amdgcn_mfma_f32_16x16x32_bf16( \
              af[ks][mi], ARR[ks*4 + ni], acc[mi][ni], 0, 0, 0); \
    __builtin_amdgcn_s_setprio(0); \
    if ((t) + 2 < nt) LDB(ARR, (t) + 2); \
    asm volatile("s_waitcnt lgkmcnt(0)" ::: "memory"); \
    __builtin_amdgcn_s_barrier(); \
    __builtin_amdgcn_sched_barrier(0); \
  } while(0)

  LDA(0); WRA(0);
  LDB(b0, 0);
  LDB(b1, 1);
  LDA(1);
  asm volatile("s_waitcnt lgkmcnt(0)" ::: "memory");
  __builtin_amdgcn_s_barrier();
  __builtin_amdgcn_sched_barrier(0);

  const int ph = lr & 7;                      // XOR term for phys A slot
  for (int t = 0; t < nt; t += 2) {
    STEP(0, b0, t);
    STEP(1, b1, t + 1);
  }
#undef LDA
#undef WRA
#undef LDB
#undef STEP

  // epilogue: D row = kq*4 + i, col = lane&15 per 16x16 frag
#pragma unroll
  for (int mi = 0; mi < 4; mi++) {
#pragma unroll
    for (int ni = 0; ni < 4; ni++) {
      const int col = gn0 + wn*64 + ni*16 + lr;
      const float bv = (ACT == 4) ? bias[col] : 0.f;
#pragma unroll
      for (int i = 0; i < 4; i++) {
        const int row = gm0 + wm*64 + mi*16 + kq*4 + i;
        if (row < M) {
          const float v = acc[mi][ni][i] + bv;
          if (ACT == 4) ((bf16_t*)C)[(size_t)row*ldc + col] = f2bf(v);
          else C[(size_t)bks*csplit + (size_t)row*ldc + col] = v;
        }
      }
    }
  }
}

// pack B (f32 [K][srcldN], transposed) -> fragment tiles for n16 groups.
__global__ void pack_bfrag(const float* __restrict__ src, bf16_t* __restrict__ dst,
                           int srcldN, int KT, int n0t, size_t in_batch, int ogb)
{
  const int ntb = blockIdx.x, kt = blockIdx.y, bz = blockIdx.z;
  src += (size_t)bz * in_batch;
  const int ng0 = n0t + bz*ogb + ntb*8;
  __shared__ float s[32][132];
  for (int i = threadIdx.x; i < 4096; i += 256) {
    const int kl = i >> 7, nl = i & 127;
    s[kl][nl] = src[(size_t)(kt*32 + kl)*srcldN + ntb*128 + nl];
  }
  __syncthreads();
  for (int u = threadIdx.x; u < 512; u += 256) {
    const int t = u >> 6, ln = u & 63;
    const int n = t*16 + (ln & 15), kq = ln >> 4;
    ushort4 v0, v1;
    v0 = make_ushort4(f2bf(s[kq*8+0][n]), f2bf(s[kq*8+1][n]), f2bf(s[kq*8+2][n]), f2bf(s[kq*8+3][n]));
    v1 = make_ushort4(f2bf(s[kq*8+4][n]), f2bf(s[kq*8+5][n]), f2bf(s[kq*8+6][n]), f2bf(s[kq*8+7][n]));
    bf16_t* dt = dst + ((size_t)(ng0 + t)*KT + kt)*512 + ln*8;
    *(ushort4*)dt = v0;
    *(ushort4*)(dt + 4) = v1;
  }
}

// sum split-K partials, add bias, write prop f32 + X right half bf16
__global__ void reduce_compress(const float* __restrict__ part, const float* __restrict__ bias,
                                float* __restrict__ prop, bf16_t* __restrict__ xr)
{
  const int idx = blockIdx.x*256 + threadIdx.x;   // < 921600
  const int m = idx >> 10, d = idx & 1023;
  float v = bias[d];
#pragma unroll
  for (int z = 0; z < 8; z++) v += part[(size_t)z*921600 + idx];
  prop[idx] = v;
  xr[(size_t)m*2048 + 1024 + d] = f2bf(v);
}

// RZ split-2 reduce: v = sigmoid(p0+p1+bias). col<1024: Xh_right = bf16(v*prop)
// col>=1024: Zbuf = v.
__global__ void reduce_rz(const float* __restrict__ part, const float* __restrict__ bias,
                          const float* __restrict__ prop, float* __restrict__ Zbuf,
                          bf16_t* __restrict__ Xh)
{
  const int idx = blockIdx.x*256 + threadIdx.x;   // < 1843200
  const int m = idx >> 11, c = idx & 2047;
  float v = part[idx] + part[1843200 + idx] + bias[c];
  v = 1.f / (1.f + __expf(-v));
  if (c < 1024) Xh[(size_t)m*2048 + 1024 + c] = f2bf(v * prop[(size_t)m*1024 + c]);
  else          Zbuf[(size_t)m*1024 + (c - 1024)] = v;
}

// h split-4 reduce: h_hat = tanh(sum+bh); prop = (1-z)*prop + z*h_hat
__global__ void reduce_h(const float* __restrict__ part, const float* __restrict__ bias,
                         const float* __restrict__ Zbuf, float* __restrict__ prop,
                         bf16_t* __restrict__ X)
{
  const int idx = blockIdx.x*256 + threadIdx.x;   // < 921600
  const int m = idx >> 10, d = idx & 1023;
  float v = bias[d];
#pragma unroll
  for (int z = 0; z < 4; z++) v += part[(size_t)z*921600 + idx];
  v = tanhf(v);
  const float zz = Zbuf[idx];
  const float pn = (1.f - zz)*prop[idx] + zz*v;
  prop[idx] = pn;
  X[(size_t)m*2048 + 1024 + d] = f2bf(pn);
}

// u_row[e][h] = sum_d W_edge[e][h][d]*W_att[e][d]; u_col with W_att[e][1024+d]
__global__ void compute_u(const float* __restrict__ We, const float* __restrict__ Wa,
                          float* __restrict__ u_row, float* __restrict__ u_col)
{
  const int w = threadIdx.x >> 6, lane = threadIdx.x & 63;
  const int idx = blockIdx.x*4 + w;               // grid=1792 -> idx<7168
  const int e = idx >> 10, h = idx & 1023;
  const float* wep = We + ((size_t)e*1024 + h)*1024;
  const float* wr  = Wa + (size_t)e*2048;
  const float* wc  = wr + 1024;
  float ar = 0.f, ac = 0.f;
#pragma unroll
  for (int t = 0; t < 16; t++) {
    const float v = wep[lane + 64*t];
    ar += v*wr[lane + 64*t];
    ac += v*wc[lane + 64*t];
  }
  for (int off = 32; off; off >>= 1) { ar += __shfl_down(ar, off); ac += __shfl_down(ac, off); }
  if (lane == 0) { u_row[idx] = ar; u_col[idx] = ac; }
}

// crc[e] = b_edge[e].Wa_row[e], crc[7+e] = b_edge[e].Wa_col[e]
__global__ void crc_kernel(const float* __restrict__ be, const float* __restrict__ Wa,
                           float* __restrict__ crc)
{
  const int w = threadIdx.x >> 6, lane = threadIdx.x & 63;
  for (int idx = w; idx < 14; idx += 4) {
    const int e = idx >> 1, which = idx & 1;
    const float* bp = be + e*1024;
    const float* wp = Wa + (size_t)e*2048 + which*1024;
    float a = 0.f;
#pragma unroll
    for (int t = 0; t < 16; t++) a += bp[lane + 64*t]*wp[lane + 64*t];
    for (int off = 32; off; off >>= 1) a += __shfl_down(a, off);
    if (lane == 0) crc[which*7 + e] = a;
  }
}

// per (b,e): scores
__global__ void attn_kernel(const float* __restrict__ prop, const float* __restrict__ u_row,
                            const float* __restrict__ u_col, const float* __restrict__ crc,
                            const float* __restrict__ b_att, float* __restrict__ scores)
{
  const int b = blockIdx.x, e = blockIdx.y;
  __shared__ float rowv[15], colv[15];
  const int w = threadIdx.x >> 6, lane = threadIdx.x & 63;
  const float* ur = u_row + (size_t)e*1024;
  const float* uc = u_col + (size_t)e*1024;
  for (int n = w; n < 15; n += 4) {
    const float* pr = prop + (size_t)(b*15 + n)*1024;
    float ar = 0.f, ac = 0.f;
#pragma unroll
    for (int t = 0; t < 16; t++) {
      const float pv = pr[lane + 64*t];
      ar += pv*ur[lane + 64*t];
      ac += pv*uc[lane + 64*t];
    }
    for (int off = 32; off; off >>= 1) { ar += __shfl_down(ar, off); ac += __shfl_down(ac, off); }
    if (lane == 0) { rowv[n] = ar; colv[n] = ac; }
  }
  __syncthreads();
  const float base = b_att[e] + crc[e] + crc[7 + e];
  for (int idx = threadIdx.x; idx < 225; idx += 256) {
    const int i = idx/15, j = idx - i*15;
    const float s = 1.f / (1.f + __expf(-(rowv[i] + colv[j] + base)));
    scores[((size_t)(b*7 + e)*15 + i)*15 + j] = s;
  }
}

// merged[b,i,d] -> X left half AND Xh left half (bf16, row-major)
__global__ void merged_kernel(const bf16_t* __restrict__ msg, const float* __restrict__ scores,
                              bf16_t* __restrict__ X, bf16_t* __restrict__ Xh)
{
  const int b = blockIdx.x, c = blockIdx.y;   // c: 128-wide d-chunk, 8 chunks
  __shared__ float ms[15*7*128];              // [j][e][dl]
  __shared__ float sc[1575];                  // [e][i][j]
  for (int q = threadIdx.x; q < 3360; q += 256) {
    const int idx = q*4;
    const int j = idx / 896;
    const int rem = idx - j*896;
    const int e = rem >> 7, dl = rem & 127;
    const ushort4 v = *(const ushort4*)(msg + (size_t)(b*15 + j)*7168 + e*1024 + c*128 + dl);
    ms[idx]   = bf2f(v.x);
    ms[idx+1] = bf2f(v.y);
    ms[idx+2] = bf2f(v.z);
    ms[idx+3] = bf2f(v.w);
  }
  for (int idx = threadIdx.x; idx < 1575; idx += 256)
    sc[idx] = scores[(size_t)b*1575 + idx];
  __syncthreads();
  for (int oi = threadIdx.x; oi < 1920; oi += 256) {
    const int i = oi >> 7, dl = oi & 127;
    float acc = 0.f;
#pragma unroll
    for (int e = 0; e < 7; e++)
#pragma unroll
      for (int j = 0; j < 15; j++)
        acc += sc[(e*15 + i)*15 + j] * ms[j*896 + e*128 + dl];
    const bf16_t o = f2bf(acc);
    X [(size_t)(b*15 + i)*2048 + c*128 + dl] = o;
    Xh[(size_t)(b*15 + i)*2048 + c*128 + dl] = o;
  }
}

__global__ void cast_f32_bf16(const float4* __restrict__ in, ushort4* __restrict__ out, int n4)
{
  int i = blockIdx.x*256 + threadIdx.x;
  const int stride = gridDim.x*256;
  for (; i < n4; i += stride) {
    const float4 v = in[i];
    out[i] = make_ushort4(f2bf(v.x), f2bf(v.y), f2bf(v.z), f2bf(v.w));
  }
}

__global__ void cat2_kernel(const float* __restrict__ a, const float* __restrict__ b,
                            float* __restrict__ o)
{
  const int i = blockIdx.x*256 + threadIdx.x;
  if (i < 1024) o[i] = a[i];
  else if (i < 2048) o[i] = b[i - 1024];
}

// final outputs from last-iteration scores
__global__ void finalize_kernel(const float* __restrict__ scores, float* __restrict__ out)
{
  const int b = blockIdx.x;   // 0..59
  __shared__ float sc[1575];
  __shared__ float act[105];
  __shared__ float asum[15];
  __shared__ float t2[7];
  for (int idx = threadIdx.x; idx < 1575; idx += 256)
    sc[idx] = scores[(size_t)b*1575 + idx];
  __syncthreads();
  for (int idx = threadIdx.x; idx < 105; idx += 256) {
    const int i = idx/7, e = idx - i*7;
    float a = 0.f;
#pragma unroll
    for (int j = 0; j < 15; j++)
      a += (1.f - sc[i*15 + j]) * sc[(e*15 + i)*15 + j];
    act[idx] = a;
    out[(size_t)b*105 + idx] = a;
  }
  for (int idx = threadIdx.x; idx < 225; idx += 256) {
    const int i = idx/15, j = idx - i*15;
    out[6660 + (size_t)b*225 + idx] = 1.f - sc[i*15 + j];
  }
  if (threadIdx.x < 15) {
    const int i = threadIdx.x;
    float s = 0.f;
#pragma unroll
    for (int j = 0; j < 15; j++) s += 1.f - sc[i*15 + j];
    asum[i] = s;
  }
  __syncthreads();
  if (threadIdx.x < 7) {
    const int e = threadIdx.x;
    float t = 0.f;
#pragma unroll
    for (int i = 0; i < 15; i++) t += act[i*7 + e]*asum[i];
    t2[e] = t;
  }
  __syncthreads();
  if (threadIdx.x == 0) {
    float mx = -1e30f;
    for (int e = 1; e < 7; e++) mx = fmaxf(mx, t2[e]);
    float s = 0.f, ex[6];
    for (int e = 1; e < 7; e++) { ex[e-1] = __expf(t2[e] - mx); s += ex[e-1]; }
    for (int e = 1; e < 7; e++) out[6300 + (size_t)b*6 + (e-1)] = ex[e-1]/s;
  }
}

extern "C" void kernel_launch(void* const* d_in, const int* in_sizes, int n_in,
                              void* d_out, int out_size, void* d_ws, size_t ws_size,
                              hipStream_t stream)
{
  const float* pose = (const float*)d_in[0];
  const float* Wc   = (const float*)d_in[1];
  const float* bc   = (const float*)d_in[2];
  const float* We   = (const float*)d_in[3];
  const float* be   = (const float*)d_in[4];
  const float* Wa   = (const float*)d_in[5];
  const float* ba   = (const float*)d_in[6];
  const float* Wr   = (const float*)d_in[7];
  const float* br   = (const float*)d_in[8];
  const float* Wz   = (const float*)d_in[9];
  const float* bz   = (const float*)d_in[10];
  const float* Wh   = (const float*)d_in[11];
  const float* bh   = (const float*)d_in[12];
  float* out = (float*)d_out;

  // ---- workspace carving ----
  char* p = (char*)d_ws;
  auto alloc = [&](size_t b) { char* r = p; p += (b + 255) & ~(size_t)255; return r; };
  bf16_t* Wedgep = (bf16_t*)alloc(448ull*32*1024);   // 14.7 MB frag [448 ng][32 kt]
  bf16_t* Wrzp   = (bf16_t*)alloc(128ull*64*1024);   //  8.4 MB frag [128 ng][64 kt]
  bf16_t* Whp    = (bf16_t*)alloc(64ull*64*1024);    //  4.2 MB frag
  bf16_t* X      = (bf16_t*)alloc(900ull*2048*2);    //  3.7 MB [merged|prop] row-major
  float*  prop   = (float*) alloc(900ull*1024*4);    //  3.7 MB f32 state
  float*  scores = (float*) alloc(60ull*7*15*15*4);
  float*  u_row  = (float*) alloc(7168*4);
  float*  u_col  = (float*) alloc(7168*4);
  float*  crc    = (float*) alloc(64);
  float*  brzv   = (float*) alloc(2048*4);
  // phase-union region (128 MB):
  // phase1 (compress): Abf 46.08 @0 | Wcp 52.4 @46.08M | partial 29.5 @98.5M
  // phase2 (iters): msgb 12.9 @0 | Zbuf @12.9M | Xh @16.6M | partRZ @20.3M
  //                 | partH @49.8M
  char* r1 = alloc(128000000ull);
  bf16_t* Abf     = (bf16_t*)r1;                     // 900x25600 bf16 row-major
  bf16_t* Wcp     = (bf16_t*)(r1 + 46080000ull);     // frag [64 ng][800 kt]
  float*  partial = (float*) (r1 + 46080000ull + 52428800ull);
  bf16_t* msgb    = (bf16_t*)r1;
  float*  Zbuf    = (float*) (r1 + 12902400ull);
  bf16_t* Xh      = (bf16_t*)(r1 + 16588800ull);
  float*  partRZ  = (float*) (r1 + 20275200ull);     // 2 x 900 x 2048 f32
  float*  partH   = (float*) (r1 + 49766400ull);     // 4 x 900 x 1024 f32

  // ---- precompute ----
  compute_u<<<1792, 256, 0, stream>>>(We, Wa, u_row, u_col);
  crc_kernel<<<1, 256, 0, stream>>>(be, Wa, crc);
  cat2_kernel<<<8, 256, 0, stream>>>(br, bz, brzv);
  cast_f32_bf16<<<2048, 256, 0, stream>>>((const float4*)pose, (ushort4*)Abf, 23040000/4);
  pack_bfrag<<<dim3(8,800), 256, 0, stream>>>(Wc, Wcp, 1024, 800, 0, 0, 0);
  pack_bfrag<<<dim3(8,32,7), 256, 0, stream>>>(We, Wedgep, 1024, 32, 0,
                                               1024ull*1024, 64);
  pack_bfrag<<<dim3(8,64), 256, 0, stream>>>(Wr, Wrzp, 1024, 64, 0, 0, 0);
  pack_bfrag<<<dim3(8,64), 256, 0, stream>>>(Wz, Wrzp, 1024, 64, 64, 0, 0);
  pack_bfrag<<<dim3(8,64), 256, 0, stream>>>(Wh, Whp, 1024, 64, 0, 0, 0);

  // compress: prop = pose @ W_compress + b_compress  (MAP1, ks=8, nt=50)
  gemm_hyb<0,1><<<dim3(8,8,8), 256, 0, stream>>>(Abf, 25600, Wcp, 800,
      partial, 1024, 921600ull, nullptr, 900, 3200);
  reduce_compress<<<3600, 256, 0, stream>>>(partial, bc, prop, X);

  // ---- 6 recurrent iterations (last one: scores only) ----
  for (int it = 0; it < 6; it++) {
    attn_kernel<<<dim3(60,7), 256, 0, stream>>>(prop, u_row, u_col, crc, ba, scores);
    if (it == 5) break;
    // msg = prop @ W_edge + b_edge  (A = X right half, row-major; MAP0, nt=16)
    gemm_hyb<4,0><<<dim3(56,8,1), 256, 0, stream>>>(X + 1024, 2048, Wedgep, 32,
        (float*)msgb, 7168, 0, be, 900, 1024);
    merged_kernel<<<dim3(60,8), 256, 0, stream>>>(msgb, scores, X, Xh);
    // [r|z] = X @ [Wr|Wz]  (MAP0, ks=2, nt=16)
    gemm_hyb<0,0><<<dim3(16,8,2), 256, 0, stream>>>(X, 2048, Wrzp, 64,
        partRZ, 2048, 1843200ull, nullptr, 900, 1024);
    reduce_rz<<<7200, 256, 0, stream>>>(partRZ, brzv, prop, Zbuf, Xh);
    // h = Xh @ Wh  (MAP0, ks=4, nt=8)
    gemm_hyb<0,0><<<dim3(8,8,4), 256, 0, stream>>>(Xh, 2048, Whp, 64,
        partH, 1024, 921600ull, nullptr, 900, 512);
    reduce_h<<<3600, 256, 0, stream>>>(partH, bh, Zbuf, prop, X);
  }

  finalize_kernel<<<60, 256, 0, stream>>>(scores, out);
}

// Round 18
// 634.646 us; speedup vs baseline: 2.2441x; 1.0404x over previous
//
#include <hip/hip_runtime.h>
#include <hip/hip_bf16.h>

typedef unsigned short bf16_t;
typedef __bf16 bf16x8 __attribute__((ext_vector_type(8)));
typedef float f32x4 __attribute__((ext_vector_type(4)));
typedef unsigned short ushort8_t __attribute__((ext_vector_type(8)));

__device__ __forceinline__ unsigned short f2bf(float x){
  union { __hip_bfloat16 h; unsigned short u; } c;
  c.h = __float2bfloat16(x);
  return c.u;
}
__device__ __forceinline__ float bf2f(bf16_t u){
  union { unsigned short u; __hip_bfloat16 h; } c;
  c.u = u;
  return __bfloat162float(c.h);
}
__device__ __forceinline__ ushort8_t cvt8v(f32x4 a, f32x4 b){
  ushort8_t r;
  r[0]=f2bf(a[0]); r[1]=f2bf(a[1]); r[2]=f2bf(a[2]); r[3]=f2bf(a[3]);
  r[4]=f2bf(b[0]); r[5]=f2bf(b[1]); r[6]=f2bf(b[2]); r[7]=f2bf(b[3]);
  return r;
}

// ---------------------------------------------------------------------------
// R13 GEMM engine (empirical optimum of 9 tested structures, 641 us wall):
// bf16 MFMA, 128x128 tile, BK=64, 4 waves (2x2), 64x64 out per wave,
// reg-staged double-buffered pipeline, conflict-free lane-linear ds_writes,
// LDS image row r at 128B with slot s holding k-group s^(r&7).
// One raw s_barrier + lgkmcnt(0) per step; no vmcnt drains.
// NEW (this round): AF32 path folds the pose f32->bf16 cast into A staging
// (loads 2x f32x4 + cvt instead of ushort8) - removes the separate cast
// kernel's 138 MB HBM round-trip. Verified pattern from R5/R6.
// MAP=0: blockIdx=(col,row,ks) -> id%8=col%8 (colTiles%8==0)
// MAP=1: blockIdx=(ks,col,row) -> id%8=ks   (split-K XCD streams)
// ACT: 0 = f32 partial store at ks*csplit; 4 = bf16 store with bias.
// Kchunk must be a multiple of 64.
// ---------------------------------------------------------------------------
template<int ACT, int MAP, int AF32>
__global__ __launch_bounds__(256, 2)
void gemm_bf16(const void* __restrict__ Aptr, int lda,
               const bf16_t* __restrict__ Bt, int ldb,
               float* __restrict__ C, int ldc, size_t csplit,
               const float* __restrict__ bias,
               int M, int N, int K, int Kchunk)
{
  __shared__ __align__(16) bf16_t As[2][128*64];   // 2 x 16 KB
  __shared__ __align__(16) bf16_t Bs[2][128*64];   // 2 x 16 KB
  const int tid = threadIdx.x;
  const int w = tid >> 6, lane = tid & 63;
  const int wm = w >> 1, wn = w & 1;
  const int lr = lane & 15, kq = lane >> 4;
  int bcol, brow, bks;
  if (MAP == 0) { bcol = blockIdx.x; brow = blockIdx.y; bks = blockIdx.z; }
  else          { bks = blockIdx.x;  bcol = blockIdx.y; brow = blockIdx.z; }
  const int gm0 = brow * 128, gn0 = bcol * 128;
  const int k0 = bks * Kchunk;
  const int nt = (min(k0 + Kchunk, K) - k0) >> 6;   // K-slabs of 64

  // staging: unit u = tid + 256*j (j=0..3) for A and for B.
  // unit u -> row u>>3, slot u&7, source k-group (u&7)^(row&7), 8 elems wide.
  const bf16_t *pA0, *pA1, *pA2, *pA3;
  const float  *pF0, *pF1, *pF2, *pF3;
  const bf16_t *pB0, *pB1, *pB2, *pB3;
  {
    const int u0 = tid,       r_0 = u0 >> 3, g0 = (u0 & 7) ^ (r_0 & 7);
    const int u1 = tid + 256, r_1 = u1 >> 3, g1 = (u1 & 7) ^ (r_1 & 7);
    const int u2 = tid + 512, r_2 = u2 >> 3, g2 = (u2 & 7) ^ (r_2 & 7);
    const int u3 = tid + 768, r_3 = u3 >> 3, g3 = (u3 & 7) ^ (r_3 & 7);
    const int m0 = min(gm0 + r_0, M-1), m1 = min(gm0 + r_1, M-1);
    const int m2 = min(gm0 + r_2, M-1), m3 = min(gm0 + r_3, M-1);
    if (AF32) {
      const float* Af = (const float*)Aptr;
      pF0 = Af + (size_t)m0*lda + k0 + g0*8;
      pF1 = Af + (size_t)m1*lda + k0 + g1*8;
      pF2 = Af + (size_t)m2*lda + k0 + g2*8;
      pF3 = Af + (size_t)m3*lda + k0 + g3*8;
      pA0 = pA1 = pA2 = pA3 = nullptr;
    } else {
      const bf16_t* Ab = (const bf16_t*)Aptr;
      pA0 = Ab + (size_t)m0*lda + k0 + g0*8;
      pA1 = Ab + (size_t)m1*lda + k0 + g1*8;
      pA2 = Ab + (size_t)m2*lda + k0 + g2*8;
      pA3 = Ab + (size_t)m3*lda + k0 + g3*8;
      pF0 = pF1 = pF2 = pF3 = nullptr;
    }
    pB0 = Bt + (size_t)min(gn0 + r_0, N-1)*ldb + k0 + g0*8;
    pB1 = Bt + (size_t)min(gn0 + r_1, N-1)*ldb + k0 + g1*8;
    pB2 = Bt + (size_t)min(gn0 + r_2, N-1)*ldb + k0 + g2*8;
    pB3 = Bt + (size_t)min(gn0 + r_3, N-1)*ldb + k0 + g3*8;
  }
  bf16_t* Al = &As[0][0] + tid*8;    // unit j at elem tid*8 + j*2048
  bf16_t* Bl = &Bs[0][0] + tid*8;
  ushort8_t va0, va1, va2, va3, vb0, vb1, vb2, vb3;

#define LDT(t) do { \
    if (AF32) { \
      va0 = cvt8v(*(const f32x4*)(pF0 + (size_t)(t)*64), *(const f32x4*)(pF0 + (size_t)(t)*64 + 4)); \
      va1 = cvt8v(*(const f32x4*)(pF1 + (size_t)(t)*64), *(const f32x4*)(pF1 + (size_t)(t)*64 + 4)); \
      va2 = cvt8v(*(const f32x4*)(pF2 + (size_t)(t)*64), *(const f32x4*)(pF2 + (size_t)(t)*64 + 4)); \
      va3 = cvt8v(*(const f32x4*)(pF3 + (size_t)(t)*64), *(const f32x4*)(pF3 + (size_t)(t)*64 + 4)); \
    } else { \
      va0 = *(const ushort8_t*)(pA0 + (size_t)(t)*64); \
      va1 = *(const ushort8_t*)(pA1 + (size_t)(t)*64); \
      va2 = *(const ushort8_t*)(pA2 + (size_t)(t)*64); \
      va3 = *(const ushort8_t*)(pA3 + (size_t)(t)*64); \
    } \
    vb0 = *(const ushort8_t*)(pB0 + (size_t)(t)*64); \
    vb1 = *(const ushort8_t*)(pB1 + (size_t)(t)*64); \
    vb2 = *(const ushort8_t*)(pB2 + (size_t)(t)*64); \
    vb3 = *(const ushort8_t*)(pB3 + (size_t)(t)*64); \
  } while(0)
#define WRT(b) do { \
    *(ushort8_t*)(Al + (b)*8192)        = va0; \
    *(ushort8_t*)(Al + (b)*8192 + 2048) = va1; \
    *(ushort8_t*)(Al + (b)*8192 + 4096) = va2; \
    *(ushort8_t*)(Al + (b)*8192 + 6144) = va3; \
    *(ushort8_t*)(Bl + (b)*8192)        = vb0; \
    *(ushort8_t*)(Bl + (b)*8192 + 2048) = vb1; \
    *(ushort8_t*)(Bl + (b)*8192 + 4096) = vb2; \
    *(ushort8_t*)(Bl + (b)*8192 + 6144) = vb3; } while(0)

  LDT(0); WRT(0);
  if (nt > 1) LDT(1);
  asm volatile("s_waitcnt lgkmcnt(0)" ::: "memory");
  __builtin_amdgcn_s_barrier();
  __builtin_amdgcn_sched_barrier(0);

  const int ph = lr & 7;                     // XOR term for phys slot
  f32x4 acc[4][4] = {};

  for (int t = 0; t < nt; ++t) {
    const int cb = t & 1;
    const bf16_t* Ab = &As[0][0] + cb*8192;
    const bf16_t* Bb = &Bs[0][0] + cb*8192;
    bf16x8 af[2][4], bfr[2][4];
#pragma unroll
    for (int ks = 0; ks < 2; ks++) {
      const int phys = (ks*4 + kq) ^ ph;     // physical 16B slot
#pragma unroll
      for (int mi = 0; mi < 4; mi++)
        af[ks][mi] = *(const bf16x8*)(Ab + (wm*64 + mi*16 + lr)*64 + phys*8);
#pragma unroll
      for (int ni = 0; ni < 4; ni++)
        bfr[ks][ni] = *(const bf16x8*)(Bb + (wn*64 + ni*16 + lr)*64 + phys*8);
    }
    if (t + 1 < nt) WRT(cb ^ 1);     // tile t+1 (regs landed; auto vmcnt wait)
    if (t + 2 < nt) LDT(t + 2);      // issue loads for t+2
    __builtin_amdgcn_s_setprio(1);
#pragma unroll
    for (int ks = 0; ks < 2; ks++)
#pragma unroll
      for (int mi = 0; mi < 4; mi++)
#pragma unroll
        for (int ni = 0; ni < 4; ni++)
          acc[mi][ni] = __builtin_amdgcn_mfma_f32_16x16x32_bf16(af[ks][mi], bfr[ks][ni], acc[mi][ni], 0, 0, 0);
    __builtin_amdgcn_s_setprio(0);
    asm volatile("s_waitcnt lgkmcnt(0)" ::: "memory");
    __builtin_amdgcn_s_barrier();
    __builtin_amdgcn_sched_barrier(0);
  }
#undef LDT
#undef WRT

  // epilogue: D row = kq*4 + i, col = lane&15 per 16x16 frag
#pragma unroll
  for (int mi = 0; mi < 4; mi++) {
#pragma unroll
    for (int ni = 0; ni < 4; ni++) {
      const int col = gn0 + wn*64 + ni*16 + lr;
      const float bv = (ACT == 4) ? bias[col] : 0.f;
#pragma unroll
      for (int i = 0; i < 4; i++) {
        const int row = gm0 + wm*64 + mi*16 + kq*4 + i;
        if (row < M) {
          const float v = acc[mi][ni][i] + bv;
          if (ACT == 4) ((bf16_t*)C)[(size_t)row*ldc + col] = f2bf(v);
          else C[(size_t)bks*csplit + (size_t)row*ldc + col] = v;
        }
      }
    }
  }
}

// sum split-K partials, add bias, write prop f32 + X right half bf16
__global__ void reduce_compress(const float* __restrict__ part, const float* __restrict__ bias,
                                float* __restrict__ prop, bf16_t* __restrict__ xr)
{
  const int idx = blockIdx.x*256 + threadIdx.x;   // < 921600
  const int m = idx >> 10, d = idx & 1023;
  float v = bias[d];
#pragma unroll
  for (int z = 0; z < 8; z++) v += part[(size_t)z*921600 + idx];
  prop[idx] = v;
  xr[(size_t)m*2048 + 1024 + d] = f2bf(v);
}

// RZ split-2 reduce: v = sigmoid(p0+p1+bias). col<1024: Xh_right = bf16(v*prop)
// col>=1024: Zbuf = v.
__global__ void reduce_rz(const float* __restrict__ part, const float* __restrict__ bias,
                          const float* __restrict__ prop, float* __restrict__ Zbuf,
                          bf16_t* __restrict__ Xh)
{
  const int idx = blockIdx.x*256 + threadIdx.x;   // < 1843200
  const int m = idx >> 11, c = idx & 2047;
  float v = part[idx] + part[1843200 + idx] + bias[c];
  v = 1.f / (1.f + __expf(-v));
  if (c < 1024) Xh[(size_t)m*2048 + 1024 + c] = f2bf(v * prop[(size_t)m*1024 + c]);
  else          Zbuf[(size_t)m*1024 + (c - 1024)] = v;
}

// h split-4 reduce: h_hat = tanh(sum+bh); prop = (1-z)*prop + z*h_hat
__global__ void reduce_h(const float* __restrict__ part, const float* __restrict__ bias,
                         const float* __restrict__ Zbuf, float* __restrict__ prop,
                         bf16_t* __restrict__ X)
{
  const int idx = blockIdx.x*256 + threadIdx.x;   // < 921600
  const int m = idx >> 10, d = idx & 1023;
  float v = bias[d];
#pragma unroll
  for (int z = 0; z < 4; z++) v += part[(size_t)z*921600 + idx];
  v = tanhf(v);
  const float zz = Zbuf[idx];
  const float pn = (1.f - zz)*prop[idx] + zz*v;
  prop[idx] = pn;
  X[(size_t)m*2048 + 1024 + d] = f2bf(pn);
}

// u_row[e][h] = sum_d W_edge[e][h][d]*W_att[e][d]; u_col with W_att[e][1024+d]
__global__ void compute_u(const float* __restrict__ We, const float* __restrict__ Wa,
                          float* __restrict__ u_row, float* __restrict__ u_col)
{
  const int w = threadIdx.x >> 6, lane = threadIdx.x & 63;
  const int idx = blockIdx.x*4 + w;               // grid=1792 -> idx<7168
  const int e = idx >> 10, h = idx & 1023;
  const float* wep = We + ((size_t)e*1024 + h)*1024;
  const float* wr  = Wa + (size_t)e*2048;
  const float* wc  = wr + 1024;
  float ar = 0.f, ac = 0.f;
#pragma unroll
  for (int t = 0; t < 16; t++) {
    const float v = wep[lane + 64*t];
    ar += v*wr[lane + 64*t];
    ac += v*wc[lane + 64*t];
  }
  for (int off = 32; off; off >>= 1) { ar += __shfl_down(ar, off); ac += __shfl_down(ac, off); }
  if (lane == 0) { u_row[idx] = ar; u_col[idx] = ac; }
}

// crc[e] = b_edge[e].Wa_row[e], crc[7+e] = b_edge[e].Wa_col[e]
__global__ void crc_kernel(const float* __restrict__ be, const float* __restrict__ Wa,
                           float* __restrict__ crc)
{
  const int w = threadIdx.x >> 6, lane = threadIdx.x & 63;
  for (int idx = w; idx < 14; idx += 4) {
    const int e = idx >> 1, which = idx & 1;
    const float* bp = be + e*1024;
    const float* wp = Wa + (size_t)e*2048 + which*1024;
    float a = 0.f;
#pragma unroll
    for (int t = 0; t < 16; t++) a += bp[lane + 64*t]*wp[lane + 64*t];
    for (int off = 32; off; off >>= 1) a += __shfl_down(a, off);
    if (lane == 0) crc[which*7 + e] = a;
  }
}

// per (b,e): row[n]=prop[b,n,:].u_row[e]; col[n]=prop[b,n,:].u_col[e]
// scores[b,e,i,j] = sigmoid(row[i]+col[j]+b_att[e]+crc_row[e]+crc_col[e])
__global__ void attn_kernel(const float* __restrict__ prop, const float* __restrict__ u_row,
                            const float* __restrict__ u_col, const float* __restrict__ crc,
                            const float* __restrict__ b_att, float* __restrict__ scores)
{
  const int b = blockIdx.x, e = blockIdx.y;
  __shared__ float rowv[15], colv[15];
  const int w = threadIdx.x >> 6, lane = threadIdx.x & 63;
  const float* ur = u_row + (size_t)e*1024;
  const float* uc = u_col + (size_t)e*1024;
  for (int n = w; n < 15; n += 4) {
    const float* pr = prop + (size_t)(b*15 + n)*1024;
    float ar = 0.f, ac = 0.f;
#pragma unroll
    for (int t = 0; t < 16; t++) {
      const float pv = pr[lane + 64*t];
      ar += pv*ur[lane + 64*t];
      ac += pv*uc[lane + 64*t];
    }
    for (int off = 32; off; off >>= 1) { ar += __shfl_down(ar, off); ac += __shfl_down(ac, off); }
    if (lane == 0) { rowv[n] = ar; colv[n] = ac; }
  }
  __syncthreads();
  const float base = b_att[e] + crc[e] + crc[7 + e];
  for (int idx = threadIdx.x; idx < 225; idx += 256) {
    const int i = idx/15, j = idx - i*15;
    const float s = 1.f / (1.f + __expf(-(rowv[i] + colv[j] + base)));
    scores[((size_t)(b*7 + e)*15 + i)*15 + j] = s;
  }
}

// merged[b,i,d] = sum_e sum_j scores[b,e,i,j]*msg[b*15+j, e*1024+d]
// -> X left half AND Xh left half (bf16)
__global__ void merged_kernel(const bf16_t* __restrict__ msg, const float* __restrict__ scores,
                              bf16_t* __restrict__ X, bf16_t* __restrict__ Xh)
{
  const int b = blockIdx.x, c = blockIdx.y;   // c: 128-wide d-chunk, 8 chunks
  __shared__ float ms[15*7*128];              // [j][e][dl]
  __shared__ float sc[1575];                  // [e][i][j]
  for (int q = threadIdx.x; q < 3360; q += 256) {     // 4-wide bf16 loads
    const int idx = q*4;
    const int j = idx / 896;
    const int rem = idx - j*896;
    const int e = rem >> 7, dl = rem & 127;
    const ushort4 v = *(const ushort4*)(msg + (size_t)(b*15 + j)*7168 + e*1024 + c*128 + dl);
    ms[idx]   = bf2f(v.x);
    ms[idx+1] = bf2f(v.y);
    ms[idx+2] = bf2f(v.z);
    ms[idx+3] = bf2f(v.w);
  }
  for (int idx = threadIdx.x; idx < 1575; idx += 256)
    sc[idx] = scores[(size_t)b*1575 + idx];
  __syncthreads();
  for (int oi = threadIdx.x; oi < 1920; oi += 256) {
    const int i = oi >> 7, dl = oi & 127;
    float acc = 0.f;
#pragma unroll
    for (int e = 0; e < 7; e++)
#pragma unroll
      for (int j = 0; j < 15; j++)
        acc += sc[(e*15 + i)*15 + j] * ms[j*896 + e*128 + dl];
    const bf16_t o = f2bf(acc);
    X [(size_t)(b*15 + i)*2048 + c*128 + dl] = o;
    Xh[(size_t)(b*15 + i)*2048 + c*128 + dl] = o;
  }
}

// 64x64-tile transpose f32 -> bf16: out[c][r] = in[r][c]  (dims %64 == 0)
__global__ void transpose_k(const float* __restrict__ in, bf16_t* __restrict__ out,
                            int R, int C, int out_ld, size_t in_batch, size_t out_batch)
{
  __shared__ float t[64][65];
  in  += (size_t)blockIdx.z * in_batch;
  out += (size_t)blockIdx.z * out_batch;
  const int r0 = blockIdx.x*64, c0 = blockIdx.y*64;
  const int tc = threadIdx.x & 63, tr = threadIdx.x >> 6;
#pragma unroll
  for (int i = 0; i < 16; i++) {
    const int r = tr*16 + i;
    t[r][tc] = in[(size_t)(r0 + r)*C + c0 + tc];
  }
  __syncthreads();
#pragma unroll
  for (int i = 0; i < 16; i++) {
    const int rr = tr*16 + i;
    out[(size_t)(c0 + rr)*out_ld + r0 + tc] = f2bf(t[tc][rr]);
  }
}

__global__ void cat2_kernel(const float* __restrict__ a, const float* __restrict__ b,
                            float* __restrict__ o)
{
  const int i = blockIdx.x*256 + threadIdx.x;
  if (i < 1024) o[i] = a[i];
  else if (i < 2048) o[i] = b[i - 1024];
}

// final outputs from last-iteration scores
__global__ void finalize_kernel(const float* __restrict__ scores, float* __restrict__ out)
{
  const int b = blockIdx.x;   // 0..59
  __shared__ float sc[1575];
  __shared__ float act[105];
  __shared__ float asum[15];
  __shared__ float t2[7];
  for (int idx = threadIdx.x; idx < 1575; idx += 256)
    sc[idx] = scores[(size_t)b*1575 + idx];
  __syncthreads();
  for (int idx = threadIdx.x; idx < 105; idx += 256) {
    const int i = idx/7, e = idx - i*7;
    float a = 0.f;
#pragma unroll
    for (int j = 0; j < 15; j++)
      a += (1.f - sc[i*15 + j]) * sc[(e*15 + i)*15 + j];
    act[idx] = a;
    out[(size_t)b*105 + idx] = a;
  }
  for (int idx = threadIdx.x; idx < 225; idx += 256) {
    const int i = idx/15, j = idx - i*15;
    out[6660 + (size_t)b*225 + idx] = 1.f - sc[i*15 + j];
  }
  if (threadIdx.x < 15) {
    const int i = threadIdx.x;
    float s = 0.f;
#pragma unroll
    for (int j = 0; j < 15; j++) s += 1.f - sc[i*15 + j];
    asum[i] = s;
  }
  __syncthreads();
  if (threadIdx.x < 7) {
    const int e = threadIdx.x;
    float t = 0.f;
#pragma unroll
    for (int i = 0; i < 15; i++) t += act[i*7 + e]*asum[i];
    t2[e] = t;
  }
  __syncthreads();
  if (threadIdx.x == 0) {
    float mx = -1e30f;
    for (int e = 1; e < 7; e++) mx = fmaxf(mx, t2[e]);
    float s = 0.f, ex[6];
    for (int e = 1; e < 7; e++) { ex[e-1] = __expf(t2[e] - mx); s += ex[e-1]; }
    for (int e = 1; e < 7; e++) out[6300 + (size_t)b*6 + (e-1)] = ex[e-1]/s;
  }
}

extern "C" void kernel_launch(void* const* d_in, const int* in_sizes, int n_in,
                              void* d_out, int out_size, void* d_ws, size_t ws_size,
                              hipStream_t stream)
{
  const float* pose = (const float*)d_in[0];
  const float* Wc   = (const float*)d_in[1];
  const float* bc   = (const float*)d_in[2];
  const float* We   = (const float*)d_in[3];
  const float* be   = (const float*)d_in[4];
  const float* Wa   = (const float*)d_in[5];
  const float* ba   = (const float*)d_in[6];
  const float* Wr   = (const float*)d_in[7];
  const float* br   = (const float*)d_in[8];
  const float* Wz   = (const float*)d_in[9];
  const float* bz   = (const float*)d_in[10];
  const float* Wh   = (const float*)d_in[11];
  const float* bh   = (const float*)d_in[12];
  float* out = (float*)d_out;

  // ---- workspace carving ----
  char* p = (char*)d_ws;
  auto alloc = [&](size_t b) { char* r = p; p += (b + 255) & ~(size_t)255; return r; };
  bf16_t* Wedge_t = (bf16_t*)alloc(7168ull*1024*2);   // [e*1024+d][h]
  bf16_t* Wrz_t   = (bf16_t*)alloc(2048ull*2048*2);   // [n][k]
  bf16_t* Wh_t    = (bf16_t*)alloc(1024ull*2048*2);   // [n][k]
  bf16_t* X       = (bf16_t*)alloc(900ull*2048*2);    // [merged | prop] bf16
  float*  prop    = (float*) alloc(900ull*1024*4);    // f32 master state
  float*  scores  = (float*) alloc(60ull*7*15*15*4);
  float*  u_row   = (float*) alloc(7168*4);
  float*  u_col   = (float*) alloc(7168*4);
  float*  crc     = (float*) alloc(64);
  float*  brzv    = (float*) alloc(2048*4);
  // phase-union region:
  // phase1 (compress): Wct 52.43 @0 | partial 29.49 @52.43M  (A = pose f32)
  // phase2 (iters): msgb 12.9 @0 | Zbuf @12.9M | Xh @16.6M | partRZ @20.3M
  //                 | partH @49.8M
  char* r1 = alloc(128000000ull);
  bf16_t* Wct     = (bf16_t*)r1;
  float*  partial = (float*) (r1 + 52428800ull);
  bf16_t* msgb    = (bf16_t*)r1;
  float*  Zbuf    = (float*) (r1 + 12902400ull);
  bf16_t* Xh      = (bf16_t*)(r1 + 16588800ull);
  float*  partRZ  = (float*) (r1 + 20275200ull);      // 2 x 900 x 2048 f32
  float*  partH   = (float*) (r1 + 49766400ull);      // 4 x 900 x 1024 f32

  // ---- precompute ----
  compute_u<<<1792, 256, 0, stream>>>(We, Wa, u_row, u_col);
  crc_kernel<<<1, 256, 0, stream>>>(be, Wa, crc);
  transpose_k<<<dim3(400,16,1), 256, 0, stream>>>(Wc, Wct, 25600, 1024, 25600, 0, 0);
  transpose_k<<<dim3(16,16,7),  256, 0, stream>>>(We, Wedge_t, 1024, 1024, 1024,
                                                  1024ull*1024, 1024ull*1024);
  transpose_k<<<dim3(32,16,1),  256, 0, stream>>>(Wr, Wrz_t, 2048, 1024, 2048, 0, 0);
  transpose_k<<<dim3(32,16,1),  256, 0, stream>>>(Wz, Wrz_t + 1024ull*2048, 2048, 1024, 2048, 0, 0);
  transpose_k<<<dim3(32,16,1),  256, 0, stream>>>(Wh, Wh_t, 2048, 1024, 2048, 0, 0);
  cat2_kernel<<<8, 256, 0, stream>>>(br, bz, brzv);

  // compress: prop = pose @ W_compress + b_compress
  // AF32: A staged straight from pose f32 (cast fused); split-K=8 (id%8=ks)
  gemm_bf16<0,1,1><<<dim3(8,8,8), 256, 0, stream>>>(pose, 25600, Wct, 25600,
      partial, 1024, 921600ull, nullptr, 900, 1024, 25600, 3200);
  reduce_compress<<<3600, 256, 0, stream>>>(partial, bc, prop, X);

  // ---- 6 recurrent iterations (last one: scores only) ----
  for (int it = 0; it < 6; it++) {
    attn_kernel<<<dim3(60,7), 256, 0, stream>>>(prop, u_row, u_col, crc, ba, scores);
    if (it == 5) break;
    // msg = prop @ W_edge + b_edge  (56 col-tiles x 8 rows, id%8=col%8, nt=16)
    gemm_bf16<4,0,0><<<dim3(56,8,1), 256, 0, stream>>>(X + 1024, 2048, Wedge_t, 1024,
        (float*)msgb, 7168, 0, be, 900, 7168, 1024, 1024);
    merged_kernel<<<dim3(60,8), 256, 0, stream>>>(msgb, scores, X, Xh);
    // [r|z] partials = X @ [Wr|Wz]  (16 cols x 8 rows x ks=2 = 256, nt=16)
    gemm_bf16<0,0,0><<<dim3(16,8,2), 256, 0, stream>>>(X, 2048, Wrz_t, 2048,
        partRZ, 2048, 1843200ull, nullptr, 900, 2048, 2048, 1024);
    reduce_rz<<<7200, 256, 0, stream>>>(partRZ, brzv, prop, Zbuf, Xh);
    // h partials = Xh @ Wh  (8 cols x 8 rows x ks=4 = 256 blocks, nt=8)
    gemm_bf16<0,0,0><<<dim3(8,8,4), 256, 0, stream>>>(Xh, 2048, Wh_t, 2048,
        partH, 1024, 921600ull, nullptr, 900, 1024, 2048, 512);
    reduce_h<<<3600, 256, 0, stream>>>(partH, bh, Zbuf, prop, X);
  }

  finalize_kernel<<<60, 256, 0, stream>>>(scores, out);
}